// Round 1
// baseline (10624.580 us; speedup 1.0000x reference)
//
#include <hip/hip_runtime.h>
#include <hip/hip_fp16.h>

namespace {

constexpr int kIn    = 64;
constexpr int kHid   = 128;
constexpr int kOut   = 64;
constexpr int kT     = 1000;
constexpr int kTC    = 8;     // timesteps per LDS staging chunk (1000 % 8 == 0)
constexpr int kBatch = 256;

__device__ __forceinline__ float sigm(float v)   { return 1.0f / (1.0f + __expf(-v)); }
__device__ __forceinline__ float tanhf_(float v) { return 2.0f / (1.0f + __expf(-2.0f * v)) - 1.0f; }

// One block per batch row (256 blocks = 1/CU). 512 threads = 8 waves.
// All weights live in per-thread VGPRs as packed f16 pairs; fmaf(float(half),f32,f32)
// folds to v_fma_mix_f32 (full fp32 VALU rate). Each thread computes 8 (or 4) output
// columns per matvec so each LDS input read feeds 8 (4) FMAs.
__global__ __launch_bounds__(512, 2) void grud_persistent(
    const float* __restrict__ gIn,
    const float* __restrict__ xMean,
    const float* __restrict__ Wdgx, const float* __restrict__ bdgx,
    const float* __restrict__ Wdgh, const float* __restrict__ bdgh,
    const float* __restrict__ Wxz,  const float* __restrict__ Whz,
    const float* __restrict__ Wmz,  const float* __restrict__ bmz,
    const float* __restrict__ Wxr,  const float* __restrict__ Whr,
    const float* __restrict__ Wmr,
    const float* __restrict__ Wxh,  const float* __restrict__ Whh,
    const float* __restrict__ Wmh,  const float* __restrict__ bmh,
    const float* __restrict__ Why,  const float* __restrict__ bhy,
    float* __restrict__ out)
{
  const int tid = threadIdx.x;
  const int b   = blockIdx.x;

  // ---------------- LDS ----------------
  __shared__ __align__(16) float sX[kTC][kIn];
  __shared__ __align__(16) float sM[kTC][kIn];
  __shared__ __align__(16) float sD[kTC][kIn];
  __shared__ __align__(16) float su[256];     // [x'(64) | m(64) | gamma_h*h (128)]
  __shared__ __align__(16) float sh[kHid];    // hidden state
  __shared__ float sxl[kIn];                  // last observed x
  __shared__ __align__(16) float srh[kHid];   // r * (gamma_h*h)
  __shared__ float sz_[kHid];                 // z gate
  __shared__ float sha[kHid];                 // x'/m part of h_tilde pre-activation
  __shared__ float Pgh[kHid][9], Pgx[kIn][9];
  __shared__ float Pz[kHid][17], Pr[kHid][17], Pha[kHid][17], Phh[kHid][17];
  __shared__ float Py[kOut][17];
  __shared__ float sBdgh[kHid], sBdgx[kIn], sBmz[kHid], sBmh[kHid], sBhy[kOut], sXm[kIn];

  // ---------- per-thread register-resident weights (packed f16 pairs) ----------
  __half2 wZR[8][8];   // tid<256: z-concat [Wxz;Wmz;Whz] | tid>=256: r-concat. 8 cols x 16 k
  __half2 wHA[4][4];   // [Wxh;Wmh] concat: 4 cols x 8 k (all threads)
  __half2 wHH[4][4];   // Whh: 4 cols x 8 k (all threads)
  __half2 wAux[8][4];  // tid<128: Wdgh | tid in [128,192): Wdgx | tid>=384: Why

  {
    const int lt = (tid < 256) ? tid : tid - 256;
    const int kc = lt & 15, cg = lt >> 4;   // cg < 16
    const float* Wx = (tid < 256) ? Wxz : Wxr;
    const float* Wm = (tid < 256) ? Wmz : Wmr;
    const float* Wh = (tid < 256) ? Whz : Whr;
#pragma unroll
    for (int c = 0; c < 8; ++c) {
      const int j = cg * 8 + c;
#pragma unroll
      for (int p = 0; p < 8; ++p) {
        const int k = kc * 16 + 2 * p;
        const float a0 = (k < 64) ? Wx[k * kHid + j]
                        : (k < 128) ? Wm[(k - 64) * kHid + j]
                                    : Wh[(k - 128) * kHid + j];
        const float a1 = (k + 1 < 64) ? Wx[(k + 1) * kHid + j]
                        : (k + 1 < 128) ? Wm[(k + 1 - 64) * kHid + j]
                                        : Wh[(k + 1 - 128) * kHid + j];
        wZR[c][p] = __floats2half2_rn(a0, a1);
      }
    }
  }
  {
    const int kc = tid & 15, cg = tid >> 4;   // cg < 32
#pragma unroll
    for (int c = 0; c < 4; ++c) {
      const int j = cg * 4 + c;
#pragma unroll
      for (int p = 0; p < 4; ++p) {
        const int k = kc * 8 + 2 * p;
        const float a0 = (k < 64) ? Wxh[k * kHid + j] : Wmh[(k - 64) * kHid + j];
        const float a1 = (k + 1 < 64) ? Wxh[(k + 1) * kHid + j] : Wmh[(k + 1 - 64) * kHid + j];
        wHA[c][p] = __floats2half2_rn(a0, a1);
        wHH[c][p] = __floats2half2_rn(Whh[k * kHid + j], Whh[(k + 1) * kHid + j]);
      }
    }
  }
  if (tid < 128) {
    const int kc = tid & 7, cg = tid >> 3;
#pragma unroll
    for (int c = 0; c < 8; ++c) {
      const int j = cg * 8 + c;
#pragma unroll
      for (int p = 0; p < 4; ++p) {
        const int k = kc * 8 + 2 * p;
        wAux[c][p] = __floats2half2_rn(Wdgh[k * kHid + j], Wdgh[(k + 1) * kHid + j]);
      }
    }
  } else if (tid < 192) {
    const int lt = tid - 128, kc = lt & 7, cg = lt >> 3;
#pragma unroll
    for (int c = 0; c < 8; ++c) {
      const int i = cg * 8 + c;
#pragma unroll
      for (int p = 0; p < 4; ++p) {
        const int k = kc * 8 + 2 * p;
        wAux[c][p] = __floats2half2_rn(Wdgx[k * kIn + i], Wdgx[(k + 1) * kIn + i]);
      }
    }
  } else if (tid >= 384) {
    const int lt = tid - 384, kc = lt & 15, cg = lt >> 4;
#pragma unroll
    for (int c = 0; c < 8; ++c) {
      const int o = cg * 8 + c;
#pragma unroll
      for (int p = 0; p < 4; ++p) {
        const int k = kc * 8 + 2 * p;
        wAux[c][p] = __floats2half2_rn(Why[k * kOut + o], Why[(k + 1) * kOut + o]);
      }
    }
  }

  if (tid < kHid) { sBdgh[tid] = bdgh[tid]; sBmz[tid] = bmz[tid]; sBmh[tid] = bmh[tid]; sh[tid] = 0.0f; }
  if (tid < kIn)  { sBdgx[tid] = bdgx[tid]; sXm[tid] = xMean[tid]; sxl[tid] = 0.0f; }
  if (tid < kOut) { sBhy[tid] = bhy[tid]; }

  const float* gBase = gIn + (size_t)b * 3 * kIn * kT;
  float* outY = out + (size_t)b * kT * kOut;
  float* outH = out + (size_t)kBatch * kT * kOut + (size_t)b * kT * kHid;

  for (int chunk = 0; chunk < kT / kTC; ++chunk) {
    const int t0 = chunk * kTC;
    // stage 8 timesteps of x/m/d into LDS, transposed to [tt][i] (coalesced float4 loads)
    if (tid < 192) {
      const int c = tid >> 6, i = tid & 63;
      const float4* src = reinterpret_cast<const float4*>(gBase + (size_t)(c * kIn + i) * kT + t0);
      const float4 v0 = src[0], v1 = src[1];
      float* dst = (c == 0) ? &sX[0][0] : (c == 1) ? &sM[0][0] : &sD[0][0];
      dst[0 * kIn + i] = v0.x; dst[1 * kIn + i] = v0.y; dst[2 * kIn + i] = v0.z; dst[3 * kIn + i] = v0.w;
      dst[4 * kIn + i] = v1.x; dst[5 * kIn + i] = v1.y; dst[6 * kIn + i] = v1.z; dst[7 * kIn + i] = v1.w;
    }
    __syncthreads();

    for (int tt = 0; tt < kTC; ++tt) {
      const int t = t0 + tt;

      // ---- Phase A compute: gamma partial dots over d (waves 0-2) ----
      if (tid < 192) {
        const bool isGH = tid < 128;
        const int lt = isGH ? tid : tid - 128;
        const int kc = lt & 7, cg = lt >> 3;
        const float4* d4 = reinterpret_cast<const float4*>(&sD[tt][kc * 8]);
        const float4 u0 = d4[0], u1 = d4[1];
        const float u[8] = {u0.x, u0.y, u0.z, u0.w, u1.x, u1.y, u1.z, u1.w};
        float acc[8];
#pragma unroll
        for (int c = 0; c < 8; ++c) {
          float a = 0.0f;
#pragma unroll
          for (int p = 0; p < 4; ++p) {
            const __half2 w = wAux[c][p];
            a = fmaf(__low2float(w),  u[2 * p],     a);
            a = fmaf(__high2float(w), u[2 * p + 1], a);
          }
          acc[c] = a;
        }
        if (isGH) {
#pragma unroll
          for (int c = 0; c < 8; ++c) Pgh[cg * 8 + c][kc] = acc[c];
        } else {
#pragma unroll
          for (int c = 0; c < 8; ++c) Pgx[cg * 8 + c][kc] = acc[c];
        }
      }
      __syncthreads();

      // ---- Phase A reduce: gamma_h*h, x' update, xl update, stage su ----
      if (tid < 128) {
        float s = sBdgh[tid];
#pragma unroll
        for (int q = 0; q < 8; ++q) s += Pgh[tid][q];
        const float gh = __expf(-fmaxf(s, 0.0f));
        su[128 + tid] = gh * sh[tid];
      } else if (tid < 192) {
        const int i = tid - 128;
        float s = sBdgx[i];
#pragma unroll
        for (int q = 0; q < 8; ++q) s += Pgx[i][q];
        const float gx = __expf(-fmaxf(s, 0.0f));
        const float x = sX[tt][i], m = sM[tt][i];
        const float xlv = (m > 0.0f) ? x : sxl[i];
        sxl[i] = xlv;
        su[i]      = m * x + (1.0f - m) * (gx * xlv + (1.0f - gx) * sXm[i]);
        su[64 + i] = m;
      }
      __syncthreads();

      // ---- Phase B compute: z (waves 0-3) / r (waves 4-7), plus [x';m] part of h_tilde (all) ----
      {
        const int lt = (tid < 256) ? tid : tid - 256;
        const int kc = lt & 15, cg = lt >> 4;
        const float4* u4 = reinterpret_cast<const float4*>(&su[kc * 16]);
        const float4 a0 = u4[0], a1 = u4[1], a2 = u4[2], a3 = u4[3];
        const float u[16] = {a0.x, a0.y, a0.z, a0.w, a1.x, a1.y, a1.z, a1.w,
                             a2.x, a2.y, a2.z, a2.w, a3.x, a3.y, a3.z, a3.w};
        float acc[8];
#pragma unroll
        for (int c = 0; c < 8; ++c) {
          float a = 0.0f;
#pragma unroll
          for (int p = 0; p < 8; ++p) {
            const __half2 w = wZR[c][p];
            a = fmaf(__low2float(w),  u[2 * p],     a);
            a = fmaf(__high2float(w), u[2 * p + 1], a);
          }
          acc[c] = a;
        }
        if (tid < 256) {
#pragma unroll
          for (int c = 0; c < 8; ++c) Pz[cg * 8 + c][kc] = acc[c];
        } else {
#pragma unroll
          for (int c = 0; c < 8; ++c) Pr[cg * 8 + c][kc] = acc[c];
        }
        // h_tilde x'/m contribution (K = su[0..127])
        const int kc2 = tid & 15, cg2 = tid >> 4;
        const float4* v4 = reinterpret_cast<const float4*>(&su[kc2 * 8]);
        const float4 b0 = v4[0], b1 = v4[1];
        const float v[8] = {b0.x, b0.y, b0.z, b0.w, b1.x, b1.y, b1.z, b1.w};
#pragma unroll
        for (int c = 0; c < 4; ++c) {
          float a = 0.0f;
#pragma unroll
          for (int p = 0; p < 4; ++p) {
            const __half2 w = wHA[c][p];
            a = fmaf(__low2float(w),  v[2 * p],     a);
            a = fmaf(__high2float(w), v[2 * p + 1], a);
          }
          Pha[cg2 * 4 + c][kc2] = a;
        }
      }
      __syncthreads();

      // ---- Phase B reduce: z gate, r*h, h_tilde partial ----
      if (tid < 128) {
        float s = sBmz[tid];
#pragma unroll
        for (int q = 0; q < 16; ++q) s += Pz[tid][q];
        sz_[tid] = sigm(s);
      } else if (tid < 256) {
        const int j = tid - 128;
        float s = 0.0f;
#pragma unroll
        for (int q = 0; q < 16; ++q) s += Pr[j][q];
        srh[j] = sigm(s) * su[128 + j];
      } else if (tid < 384) {
        const int j = tid - 256;
        float s = sBmh[j];
#pragma unroll
        for (int q = 0; q < 16; ++q) s += Pha[j][q];
        sha[j] = s;
      }
      __syncthreads();

      // ---- Phase C compute: (r*h) @ W_hh (all waves) ----
      {
        const int kc = tid & 15, cg = tid >> 4;
        const float4* v4 = reinterpret_cast<const float4*>(&srh[kc * 8]);
        const float4 b0 = v4[0], b1 = v4[1];
        const float v[8] = {b0.x, b0.y, b0.z, b0.w, b1.x, b1.y, b1.z, b1.w};
#pragma unroll
        for (int c = 0; c < 4; ++c) {
          float a = 0.0f;
#pragma unroll
          for (int p = 0; p < 4; ++p) {
            const __half2 w = wHH[c][p];
            a = fmaf(__low2float(w),  v[2 * p],     a);
            a = fmaf(__high2float(w), v[2 * p + 1], a);
          }
          Phh[cg * 4 + c][kc] = a;
        }
      }
      __syncthreads();

      // ---- Phase C reduce: h update + hs output ----
      if (tid < 128) {
        float s = sha[tid];
#pragma unroll
        for (int q = 0; q < 16; ++q) s += Phh[tid][q];
        const float ht = tanhf_(s);
        const float hp = su[128 + tid];
        const float z  = sz_[tid];
        const float hn = (1.0f - z) * hp + z * ht;
        sh[tid] = hn;
        outH[(size_t)t * kHid + tid] = hn;
      }
      __syncthreads();

      // ---- Phase D compute: y partials (waves 6-7) ----
      if (tid >= 384) {
        const int lt = tid - 384, kc = lt & 15, cg = lt >> 4;
        const float4* v4 = reinterpret_cast<const float4*>(&sh[kc * 8]);
        const float4 b0 = v4[0], b1 = v4[1];
        const float v[8] = {b0.x, b0.y, b0.z, b0.w, b1.x, b1.y, b1.z, b1.w};
        float acc[8];
#pragma unroll
        for (int c = 0; c < 8; ++c) {
          float a = 0.0f;
#pragma unroll
          for (int p = 0; p < 4; ++p) {
            const __half2 w = wAux[c][p];
            a = fmaf(__low2float(w),  v[2 * p],     a);
            a = fmaf(__high2float(w), v[2 * p + 1], a);
          }
          acc[c] = a;
        }
#pragma unroll
        for (int c = 0; c < 8; ++c) Py[cg * 8 + c][kc] = acc[c];
      }
      __syncthreads();

      // ---- Phase D reduce: y output ----
      if (tid < 64) {
        float s = sBhy[tid];
#pragma unroll
        for (int q = 0; q < 16; ++q) s += Py[tid][q];
        outY[(size_t)t * kOut + tid] = sigm(s);
      }
      // no barrier needed: next write to Py is after 6 barriers of next step
    }
  }
}

} // namespace

extern "C" void kernel_launch(void* const* d_in, const int* in_sizes, int n_in,
                              void* d_out, int out_size, void* d_ws, size_t ws_size,
                              hipStream_t stream) {
  const float* gIn   = (const float*)d_in[0];
  const float* xMean = (const float*)d_in[1];
  const float* Wdgx  = (const float*)d_in[2];
  const float* bdgx  = (const float*)d_in[3];
  const float* Wdgh  = (const float*)d_in[4];
  const float* bdgh  = (const float*)d_in[5];
  const float* Wxz   = (const float*)d_in[6];
  const float* Whz   = (const float*)d_in[7];
  const float* Wmz   = (const float*)d_in[8];
  const float* bmz   = (const float*)d_in[9];
  const float* Wxr   = (const float*)d_in[10];
  const float* Whr   = (const float*)d_in[11];
  const float* Wmr   = (const float*)d_in[12];
  const float* Wxh   = (const float*)d_in[13];
  const float* Whh   = (const float*)d_in[14];
  const float* Wmh   = (const float*)d_in[15];
  const float* bmh   = (const float*)d_in[16];
  const float* Why   = (const float*)d_in[17];
  const float* bhy   = (const float*)d_in[18];

  grud_persistent<<<dim3(256), dim3(512), 0, stream>>>(
      gIn, xMean, Wdgx, bdgx, Wdgh, bdgh, Wxz, Whz, Wmz, bmz,
      Wxr, Whr, Wmr, Wxh, Whh, Wmh, bmh, Why, bhy, (float*)d_out);
}